// Round 6
// baseline (135.587 us; speedup 1.0000x reference)
//
#include <hip/hip_runtime.h>
#include <hip/hip_bf16.h>
#include <math.h>

typedef __attribute__((ext_vector_type(8))) short short8;
typedef __attribute__((ext_vector_type(4))) float f32x4;
typedef unsigned int uint;
typedef unsigned short ushort;

#define HWSZ 16384
#define PADW 130
#define SLAB (PADW*PADW*64)

__device__ __forceinline__ uint pk2bf(float a, float b) {
    union { __hip_bfloat162 h; uint u; } cv;
    cv.h = __float22bfloat162_rn(make_float2(a, b)); return cv.u;
}
__device__ __forceinline__ float bflo(uint u){ return __uint_as_float(u << 16); }
__device__ __forceinline__ float bfhi(uint u){ return __uint_as_float(u & 0xffff0000u); }

// ---------------------------------------------------------------------------
// bilinear combine of 4 corner short8's (8 bf16 channels) -> bf16 A-frag
// ---------------------------------------------------------------------------
__device__ __forceinline__ short8 combine4(short8 s0, short8 s1, short8 s2, short8 s3,
                                           float g0, float g1, float g2, float g3)
{
    uint4 u0 = *(uint4*)&s0, u1 = *(uint4*)&s1, u2 = *(uint4*)&s2, u3 = *(uint4*)&s3;
    float v0,v1,v2,v3,v4,v5,v6,v7;
    v0 = g0*bflo(u0.x); v1 = g0*bfhi(u0.x); v2 = g0*bflo(u0.y); v3 = g0*bfhi(u0.y);
    v4 = g0*bflo(u0.z); v5 = g0*bfhi(u0.z); v6 = g0*bflo(u0.w); v7 = g0*bfhi(u0.w);
    v0 = fmaf(g1,bflo(u1.x),v0); v1 = fmaf(g1,bfhi(u1.x),v1);
    v2 = fmaf(g1,bflo(u1.y),v2); v3 = fmaf(g1,bfhi(u1.y),v3);
    v4 = fmaf(g1,bflo(u1.z),v4); v5 = fmaf(g1,bfhi(u1.z),v5);
    v6 = fmaf(g1,bflo(u1.w),v6); v7 = fmaf(g1,bfhi(u1.w),v7);
    v0 = fmaf(g2,bflo(u2.x),v0); v1 = fmaf(g2,bfhi(u2.x),v1);
    v2 = fmaf(g2,bflo(u2.y),v2); v3 = fmaf(g2,bfhi(u2.y),v3);
    v4 = fmaf(g2,bflo(u2.z),v4); v5 = fmaf(g2,bfhi(u2.z),v5);
    v6 = fmaf(g2,bflo(u2.w),v6); v7 = fmaf(g2,bfhi(u2.w),v7);
    v0 = fmaf(g3,bflo(u3.x),v0); v1 = fmaf(g3,bfhi(u3.x),v1);
    v2 = fmaf(g3,bflo(u3.y),v2); v3 = fmaf(g3,bfhi(u3.y),v3);
    v4 = fmaf(g3,bflo(u3.z),v4); v5 = fmaf(g3,bfhi(u3.z),v5);
    v6 = fmaf(g3,bflo(u3.w),v6); v7 = fmaf(g3,bfhi(u3.w),v7);
    union { short8 s; uint u[4]; } r;
    r.u[0] = pk2bf(v0,v1); r.u[1] = pk2bf(v2,v3);
    r.u[2] = pk2bf(v4,v5); r.u[3] = pk2bf(v6,v7);
    return r.s;
}

// coords for one tap -> 4 corner byte-offsets + 4 mask-scaled bilinear gains
__device__ __forceinline__ void coords_tap(
    const float* __restrict__ omW, int px, int irow, int jcol, int n,
    int4& ba, float4& bg)
{
    int di = n / 3, dj = n - di * 3;
    float offx = omW[n * 17 + px];
    float offy = omW[(9 + n) * 17 + px];
    float mv   = omW[(18 + n) * 17 + px];
    float pxf = (float)(irow + di) + offx;
    float pyf = (float)(jcol + dj) + offy;
    float fx = floorf(pxf), fy = floorf(pyf);
    float qltx = fminf(fmaxf(fx,       0.f), 129.f);
    float qlty = fminf(fmaxf(fy,       0.f), 129.f);
    float qrbx = fminf(fmaxf(fx + 1.f, 0.f), 129.f);
    float qrby = fminf(fmaxf(fy + 1.f, 0.f), 129.f);
    float pxc  = fminf(fmaxf(pxf,      0.f), 129.f);
    float pyc  = fminf(fmaxf(pyf,      0.f), 129.f);
    float glt = (1.f + (qltx - pxc)) * (1.f + (qlty - pyc));
    float grb = (1.f - (qrbx - pxc)) * (1.f - (qrby - pyc));
    float glb = (1.f + (qltx - pxc)) * (1.f - (qrby - pyc));
    float grt = (1.f - (qrbx - pxc)) * (1.f + (qlty - pyc));
    int ltx = (int)qltx, lty = (int)qlty, rbx = (int)qrbx, rby = (int)qrby;
    ba.x = (ltx * PADW + lty) * 128;
    ba.y = (rbx * PADW + rby) * 128;
    ba.z = (ltx * PADW + rby) * 128;
    ba.w = (rbx * PADW + lty) * 128;
    bg.x = glt * mv; bg.y = grb * mv; bg.z = glb * mv; bg.w = grt * mv;
}

// ---------------------------------------------------------------------------
// prep_x: blocks [0,128): NCHW fp32 -> padded NHWC bf16 (2-ch packed writes)
//         blocks [128,1160): zero borders of xt and y1t (all 4 batches)
// ---------------------------------------------------------------------------
__global__ __launch_bounds__(256, 2) void prep_x(
    const float* __restrict__ x, ushort* __restrict__ xtt, ushort* __restrict__ y1t)
{
    int t = threadIdx.x, l = t & 63, wv = t >> 6;
    if (blockIdx.x < 128) {
        int c2 = l & 31, ps = l >> 5;
        int pix0w = blockIdx.x * 512 + wv * 128;
        int bq = pix0w >> 14;
        const float* xp0 = x + ((size_t)(bq * 64 + c2 * 2)) * HWSZ;
        ushort* xw = xtt + (size_t)bq * SLAB;
        #pragma unroll 8
        for (int p = 0; p < 64; ++p) {
            int pxi = (pix0w + p * 2 + ps) & (HWSZ - 1);
            int i = pxi >> 7, j = pxi & 127;
            uint u = pk2bf(xp0[pxi], xp0[pxi + HWSZ]);
            *(uint*)(xw + ((i + 1) * PADW + (j + 1)) * 64 + c2 * 2) = u;
        }
    } else {
        int idx = (blockIdx.x - 128) * 256 + t;
        if (idx >= 264192) return;
        ushort* buf = (idx >= 132096) ? y1t : xtt;
        int e_all = idx % 132096;
        int bq = e_all / 33024, e = e_all % 33024;
        int i, j, c;
        if (e < 8320)       { i = 0;   j = e >> 6; c = e & 63; }
        else if (e < 16640) { int e2 = e - 8320; i = 129; j = e2 >> 6; c = e2 & 63; }
        else                { int e2 = e - 16640; c = e2 & 63;
                              i = (e2 >> 7) + 1; j = ((e2 >> 6) & 1) ? 129 : 0; }
        buf[(size_t)bq * SLAB + (i * PADW + j) * 64 + c] = 0;
    }
}

// ---------------------------------------------------------------------------
// prep_w: all four fragment-major weight buffers in one dispatch.
// Layer split by explicit subtraction (36864/18432 are NOT powers of 2).
// ---------------------------------------------------------------------------
__global__ void prep_w(
    const float* __restrict__ wc1, const float* __restrict__ wp1, const float* __restrict__ wm1,
    const float* __restrict__ wc2, const float* __restrict__ wp2, const float* __restrict__ wm2,
    ushort* __restrict__ wdf1, ushort* __restrict__ wof1,
    ushort* __restrict__ wdf2, ushort* __restrict__ wof2)
{
    int idx0 = blockIdx.x * 256 + threadIdx.x;
    union { __hip_bfloat16 h; ushort u; } cv;
    if (idx0 < 73728) {
        int lay = idx0 >= 36864;
        int idx = idx0 - lay * 36864;
        const float* wc = lay ? wc2 : wc1;
        ushort* dst = lay ? wdf2 : wdf1;
        int j = idx & 7, l = (idx >> 3) & 63;
        int nt = (idx >> 9) & 3, kc = (idx >> 11) & 1, tap = idx >> 12;
        int c  = kc * 32 + (l >> 4) * 8 + j;
        int oc = nt * 16 + (l & 15);
        cv.h = __float2bfloat16(wc[(oc * 64 + c) * 9 + tap]);
        dst[idx] = cv.u;
    } else if (idx0 < 110592) {
        int r = idx0 - 73728;
        int lay = r >= 18432;
        int idx = r - lay * 18432;
        const float* wp = lay ? wp2 : wp1;
        const float* wm = lay ? wm2 : wm1;
        ushort* dst = lay ? wof2 : wof1;
        int j = idx & 7, l = (idx >> 3) & 63;
        int nt = (idx >> 9) & 1, kc = (idx >> 10) & 1, tap = idx >> 11;
        int c  = kc * 32 + (l >> 4) * 8 + j;
        int ch = nt * 16 + (l & 15);
        float v = 0.f;
        if (ch < 18)      v = wp[(ch * 64 + c) * 9 + tap];
        else if (ch < 27) v = wm[((ch - 18) * 64 + c) * 9 + tap];
        cv.h = __float2bfloat16(v);
        dst[idx] = cv.u;
    }
}

// ---------------------------------------------------------------------------
// Fused modulated-deformable-conv layer. 256 thr / 4 waves / 64 px (half row).
//  phase 1: offset/mask 3x3 conv via direct-load MFMA -> wave-private LDS
//  phase 2/3: depth-2 software-pipelined tap loop: coords+corner-gathers for
//           tap n+1 issued before combine(tap n); weight loads hoisted above
//           their combine so combine VALU covers the L2 latency.
//  XCD-swizzled blockIdx for gather L2 locality.
// ---------------------------------------------------------------------------
__global__ __launch_bounds__(256, 3) void fused(
    const ushort* __restrict__ xt, const ushort* __restrict__ wof,
    const float* __restrict__ bp, const float* __restrict__ bm,
    const ushort* __restrict__ wdf, const float* __restrict__ xres,
    float* __restrict__ outn, ushort* __restrict__ y1t, int mode)
{
    __shared__ __align__(16) char sm[16384];
    const int t = threadIdx.x, l = t & 63, wv = t >> 6;
    // XCD swizzle: grid=1024 (%8==0) -> XCD k gets logical blocks [k*128,(k+1)*128)
    const int lb = (blockIdx.x & 7) * 128 + (blockIdx.x >> 3);
    const int pix0 = lb * 64;
    const int bb = pix0 >> 14, pxb = pix0 & (HWSZ - 1);
    const int irow = pxb >> 7;
    const int j0 = (pxb & 127) + wv * 16;      // wave's first pixel column
    const int px = l & 15, ck = l >> 4;        // lane's pixel / channel-chunk
    const ushort* xb = xt + (size_t)bb * SLAB;

    // ---------- phase 1: offset/mask conv ----------
    f32x4 z4 = {0.f, 0.f, 0.f, 0.f};
    f32x4 oa0 = z4, oa1 = z4;
    #pragma unroll
    for (int tap = 0; tap < 9; ++tap) {
        int ti = tap / 3, tj = tap - ti * 3;
        const ushort* ap = xb + ((irow + ti) * PADW + j0 + px + tj) * 64 + ck * 8;
        short8 a0 = *(const short8*)ap;
        short8 a1 = *(const short8*)(ap + 32);
        short8 b00 = *(const short8*)(wof + (tap * 4 + 0) * 512 + l * 8);
        short8 b01 = *(const short8*)(wof + (tap * 4 + 1) * 512 + l * 8);
        short8 b10 = *(const short8*)(wof + (tap * 4 + 2) * 512 + l * 8);
        short8 b11 = *(const short8*)(wof + (tap * 4 + 3) * 512 + l * 8);
        oa0 = __builtin_amdgcn_mfma_f32_16x16x32_bf16(a0, b00, oa0, 0, 0, 0);
        oa1 = __builtin_amdgcn_mfma_f32_16x16x32_bf16(a0, b01, oa1, 0, 0, 0);
        oa0 = __builtin_amdgcn_mfma_f32_16x16x32_bf16(a1, b10, oa0, 0, 0, 0);
        oa1 = __builtin_amdgcn_mfma_f32_16x16x32_bf16(a1, b11, oa1, 0, 0, 0);
    }
    float* omW = ((float*)sm) + wv * 544;      // [27][16] stride 17
    #pragma unroll
    for (int nt = 0; nt < 2; ++nt) {
        f32x4 oa = nt ? oa1 : oa0;
        int ch = nt * 16 + px;                 // D-layout: col(l&15)=ch
        #pragma unroll
        for (int r = 0; r < 4; ++r) {
            int pxl = ck * 4 + r;              // D-layout: row=pixel
            if (ch < 27) {
                float v = oa[r] + ((ch < 18) ? bp[ch] : bm[ch - 18]);
                if (ch >= 18) v = 1.f / (1.f + __expf(-v));
                omW[ch * 17 + pxl] = v;
            }
        }
    }

    // ---------- phase 2/3: pipelined deformable sampling + contraction ----------
    f32x4 acc0 = z4, acc1 = z4, acc2 = z4, acc3 = z4;
    const char* pbase = (const char*)xb + ck * 16;
    const int jcol = j0 + px;

    int4  ba[2]; float4 bg[2];
    short8 cb[2][8];

    coords_tap(omW, px, irow, jcol, 0, ba[0], bg[0]);
    {
        int4 b0 = ba[0];
        cb[0][0] = *(const short8*)(pbase + b0.x); cb[0][1] = *(const short8*)(pbase + b0.x + 64);
        cb[0][2] = *(const short8*)(pbase + b0.y); cb[0][3] = *(const short8*)(pbase + b0.y + 64);
        cb[0][4] = *(const short8*)(pbase + b0.z); cb[0][5] = *(const short8*)(pbase + b0.z + 64);
        cb[0][6] = *(const short8*)(pbase + b0.w); cb[0][7] = *(const short8*)(pbase + b0.w + 64);
    }

    #pragma unroll
    for (int n = 0; n < 9; ++n) {
        const int cur = n & 1, nxt = cur ^ 1;
        if (n < 8) {
            coords_tap(omW, px, irow, jcol, n + 1, ba[nxt], bg[nxt]);
            int4 bn = ba[nxt];
            cb[nxt][0] = *(const short8*)(pbase + bn.x); cb[nxt][1] = *(const short8*)(pbase + bn.x + 64);
            cb[nxt][2] = *(const short8*)(pbase + bn.y); cb[nxt][3] = *(const short8*)(pbase + bn.y + 64);
            cb[nxt][4] = *(const short8*)(pbase + bn.z); cb[nxt][5] = *(const short8*)(pbase + bn.z + 64);
            cb[nxt][6] = *(const short8*)(pbase + bn.w); cb[nxt][7] = *(const short8*)(pbase + bn.w + 64);
        }
        const ushort* wbase = wdf + (size_t)n * 4096 + l * 8;
        float4 g = bg[cur];
        // first K-half: issue weights, combine (covers weight latency), MFMA
        short8 w00 = *(const short8*)(wbase);
        short8 w01 = *(const short8*)(wbase + 512);
        short8 w02 = *(const short8*)(wbase + 1024);
        short8 w03 = *(const short8*)(wbase + 1536);
        short8 a0 = combine4(cb[cur][0], cb[cur][2], cb[cur][4], cb[cur][6],
                             g.x, g.y, g.z, g.w);
        acc0 = __builtin_amdgcn_mfma_f32_16x16x32_bf16(a0, w00, acc0, 0, 0, 0);
        acc1 = __builtin_amdgcn_mfma_f32_16x16x32_bf16(a0, w01, acc1, 0, 0, 0);
        acc2 = __builtin_amdgcn_mfma_f32_16x16x32_bf16(a0, w02, acc2, 0, 0, 0);
        acc3 = __builtin_amdgcn_mfma_f32_16x16x32_bf16(a0, w03, acc3, 0, 0, 0);
        // second K-half
        short8 w10 = *(const short8*)(wbase + 2048);
        short8 w11 = *(const short8*)(wbase + 2560);
        short8 w12 = *(const short8*)(wbase + 3072);
        short8 w13 = *(const short8*)(wbase + 3584);
        short8 a1 = combine4(cb[cur][1], cb[cur][3], cb[cur][5], cb[cur][7],
                             g.x, g.y, g.z, g.w);
        acc0 = __builtin_amdgcn_mfma_f32_16x16x32_bf16(a1, w10, acc0, 0, 0, 0);
        acc1 = __builtin_amdgcn_mfma_f32_16x16x32_bf16(a1, w11, acc1, 0, 0, 0);
        acc2 = __builtin_amdgcn_mfma_f32_16x16x32_bf16(a1, w12, acc2, 0, 0, 0);
        acc3 = __builtin_amdgcn_mfma_f32_16x16x32_bf16(a1, w13, acc3, 0, 0, 0);
    }

    // ---------- epilogue ----------
    if (mode == 0) {
        // +residual -> NCHW fp32, direct float4 stores (4 consecutive px per lane)
        int pxi0 = pxb + wv * 16 + ck * 4;
        f32x4 av[4] = {acc0, acc1, acc2, acc3};
        #pragma unroll
        for (int nt = 0; nt < 4; ++nt) {
            int oc = nt * 16 + px;
            size_t o = ((size_t)(bb * 64 + oc)) * HWSZ + pxi0;
            float4 rsd = *(const float4*)(xres + o);
            float4 vv;
            vv.x = av[nt][0] + rsd.x; vv.y = av[nt][1] + rsd.y;
            vv.z = av[nt][2] + rsd.z; vv.w = av[nt][3] + rsd.w;
            *(float4*)(outn + o) = vv;
        }
    } else {
        // relu -> padded NHWC bf16 via LDS transpose
        __syncthreads();
        float* T = (float*)sm;
        f32x4 av[4] = {acc0, acc1, acc2, acc3};
        #pragma unroll
        for (int nt = 0; nt < 4; ++nt) {
            int oc = nt * 16 + px;
            #pragma unroll
            for (int r = 0; r < 4; ++r) {
                int pxl = wv * 16 + ck * 4 + r;
                T[oc * 64 + (pxl ^ (oc & 31))] = fmaxf(av[nt][r], 0.f);
            }
        }
        __syncthreads();
        int pxx = t & 63, cg = t >> 6;
        int pxi = pxb + pxx;
        int i = pxi >> 7, j = pxi & 127;
        ushort* dst = y1t + (size_t)bb * SLAB + ((i + 1) * PADW + (j + 1)) * 64 + cg * 16;
        uint w[8];
        #pragma unroll
        for (int k2 = 0; k2 < 8; ++k2) {
            int oc0 = cg * 16 + k2 * 2;
            float a0 = T[oc0 * 64 + (pxx ^ (oc0 & 31))];
            float a1 = T[(oc0 + 1) * 64 + (pxx ^ ((oc0 + 1) & 31))];
            w[k2] = pk2bf(a0, a1);
        }
        *(uint4*)dst = make_uint4(w[0], w[1], w[2], w[3]);
        *(uint4*)(dst + 8) = make_uint4(w[4], w[5], w[6], w[7]);
    }
}

// ---------------------------------------------------------------------------
extern "C" void kernel_launch(void* const* d_in, const int* in_sizes, int n_in,
                              void* d_out, int out_size, void* d_ws, size_t ws_size,
                              hipStream_t stream)
{
    const float* x      = (const float*)d_in[0];
    const float* d1_w_p = (const float*)d_in[1];
    const float* d1_b_p = (const float*)d_in[2];
    const float* d1_w_m = (const float*)d_in[3];
    const float* d1_b_m = (const float*)d_in[4];
    const float* d1_w_c = (const float*)d_in[5];
    const float* d2_w_p = (const float*)d_in[6];
    const float* d2_b_p = (const float*)d_in[7];
    const float* d2_w_m = (const float*)d_in[8];
    const float* d2_b_m = (const float*)d_in[9];
    const float* d2_w_c = (const float*)d_in[10];
    float* out = (float*)d_out;

    char* ws = (char*)d_ws;
    ushort* xtt  = (ushort*)(ws);               //  8,652,800 B padded NHWC bf16 x
    ushort* y1t  = (ushort*)(ws + 8652800);     //  8,652,800 B padded NHWC bf16 y1
    ushort* wdf1 = (ushort*)(ws + 17305600);    //     73,728 B
    ushort* wof1 = (ushort*)(ws + 17379328);    //     36,864 B
    ushort* wdf2 = (ushort*)(ws + 17416192);    //     73,728 B
    ushort* wof2 = (ushort*)(ws + 17489920);    //     36,864 B

    prep_w<<<432, 256, 0, stream>>>(d1_w_c, d1_w_p, d1_w_m, d2_w_c, d2_w_p, d2_w_m,
                                    wdf1, wof1, wdf2, wof2);
    prep_x<<<1160, 256, 0, stream>>>(x, xtt, y1t);

    fused<<<1024, 256, 0, stream>>>(xtt, wof1, d1_b_p, d1_b_m, wdf1,
                                    nullptr, nullptr, y1t, 1);
    fused<<<1024, 256, 0, stream>>>(y1t, wof2, d2_b_p, d2_b_m, wdf2,
                                    x, out, nullptr, 0);
}

// Round 7
// 83.327 us; speedup vs baseline: 1.6272x; 1.6272x over previous
//
#include <hip/hip_runtime.h>
#include <hip/hip_bf16.h>
#include <math.h>

typedef __attribute__((ext_vector_type(8))) short short8;
typedef __attribute__((ext_vector_type(4))) float f32x4;
typedef unsigned int uint;
typedef unsigned short ushort;

#define HWSZ 16384
#define PADW 130
#define SLAB (PADW*PADW*64)
// window geometry: 16 rows x 24 cols of 128B cells, origin (i0-2, j0-2) in padded coords
#define WR 16
#define WC 24
#define OMW_OFF 49152           // bytes; omW after window
#define SM_BYTES (49152 + 4*27*33*4)

__device__ __forceinline__ uint pk2bf(float a, float b) {
    union { __hip_bfloat162 h; uint u; } cv;
    cv.h = __float22bfloat162_rn(make_float2(a, b)); return cv.u;
}
__device__ __forceinline__ float bflo(uint u){ return __uint_as_float(u << 16); }
__device__ __forceinline__ float bfhi(uint u){ return __uint_as_float(u & 0xffff0000u); }

__device__ __forceinline__ short8 combine4(short8 s0, short8 s1, short8 s2, short8 s3,
                                           float g0, float g1, float g2, float g3)
{
    uint4 u0 = *(uint4*)&s0, u1 = *(uint4*)&s1, u2 = *(uint4*)&s2, u3 = *(uint4*)&s3;
    float v0,v1,v2,v3,v4,v5,v6,v7;
    v0 = g0*bflo(u0.x); v1 = g0*bfhi(u0.x); v2 = g0*bflo(u0.y); v3 = g0*bfhi(u0.y);
    v4 = g0*bflo(u0.z); v5 = g0*bfhi(u0.z); v6 = g0*bflo(u0.w); v7 = g0*bfhi(u0.w);
    v0 = fmaf(g1,bflo(u1.x),v0); v1 = fmaf(g1,bfhi(u1.x),v1);
    v2 = fmaf(g1,bflo(u1.y),v2); v3 = fmaf(g1,bfhi(u1.y),v3);
    v4 = fmaf(g1,bflo(u1.z),v4); v5 = fmaf(g1,bfhi(u1.z),v5);
    v6 = fmaf(g1,bflo(u1.w),v6); v7 = fmaf(g1,bfhi(u1.w),v7);
    v0 = fmaf(g2,bflo(u2.x),v0); v1 = fmaf(g2,bfhi(u2.x),v1);
    v2 = fmaf(g2,bflo(u2.y),v2); v3 = fmaf(g2,bfhi(u2.y),v3);
    v4 = fmaf(g2,bflo(u2.z),v4); v5 = fmaf(g2,bfhi(u2.z),v5);
    v6 = fmaf(g2,bflo(u2.w),v6); v7 = fmaf(g2,bfhi(u2.w),v7);
    v0 = fmaf(g3,bflo(u3.x),v0); v1 = fmaf(g3,bfhi(u3.x),v1);
    v2 = fmaf(g3,bflo(u3.y),v2); v3 = fmaf(g3,bfhi(u3.y),v3);
    v4 = fmaf(g3,bflo(u3.z),v4); v5 = fmaf(g3,bfhi(u3.z),v5);
    v6 = fmaf(g3,bflo(u3.w),v6); v7 = fmaf(g3,bfhi(u3.w),v7);
    union { short8 s; uint u[4]; } r;
    r.u[0] = pk2bf(v0,v1); r.u[1] = pk2bf(v2,v3);
    r.u[2] = pk2bf(v4,v5); r.u[3] = pk2bf(v6,v7);
    return r.s;
}

// coords for one tap/px -> integer corner coords (padded frame) + mask-scaled gains
__device__ __forceinline__ void coords_tap(
    const float* __restrict__ omW, int px32, int irow, int jcol, int n,
    int4& cc, float4& bg)
{
    int di = n / 3, dj = n - di * 3;
    float offx = omW[n * 33 + px32];
    float offy = omW[(9 + n) * 33 + px32];
    float mv   = omW[(18 + n) * 33 + px32];
    float pxf = (float)(irow + di) + offx;
    float pyf = (float)(jcol + dj) + offy;
    float fx = floorf(pxf), fy = floorf(pyf);
    float qltx = fminf(fmaxf(fx,       0.f), 129.f);
    float qlty = fminf(fmaxf(fy,       0.f), 129.f);
    float qrbx = fminf(fmaxf(fx + 1.f, 0.f), 129.f);
    float qrby = fminf(fmaxf(fy + 1.f, 0.f), 129.f);
    float pxc  = fminf(fmaxf(pxf,      0.f), 129.f);
    float pyc  = fminf(fmaxf(pyf,      0.f), 129.f);
    float glt = (1.f + (qltx - pxc)) * (1.f + (qlty - pyc));
    float grb = (1.f - (qrbx - pxc)) * (1.f - (qrby - pyc));
    float glb = (1.f + (qltx - pxc)) * (1.f - (qrby - pyc));
    float grt = (1.f - (qrbx - pxc)) * (1.f + (qlty - pyc));
    cc.x = (int)qltx; cc.y = (int)qlty; cc.z = (int)qrbx; cc.w = (int)qrby;
    bg.x = glt * mv; bg.y = grb * mv; bg.z = glb * mv; bg.w = grt * mv;
}

// ---------------------------------------------------------------------------
// prep_x: blocks [0,128): NCHW fp32 -> padded NHWC bf16
//         blocks [128,1160): zero borders of xt and y1t
// ---------------------------------------------------------------------------
__global__ __launch_bounds__(256, 2) void prep_x(
    const float* __restrict__ x, ushort* __restrict__ xtt, ushort* __restrict__ y1t)
{
    int t = threadIdx.x, l = t & 63, wv = t >> 6;
    if (blockIdx.x < 128) {
        int c2 = l & 31, ps = l >> 5;
        int pix0w = blockIdx.x * 512 + wv * 128;
        int bq = pix0w >> 14;
        const float* xp0 = x + ((size_t)(bq * 64 + c2 * 2)) * HWSZ;
        ushort* xw = xtt + (size_t)bq * SLAB;
        #pragma unroll 8
        for (int p = 0; p < 64; ++p) {
            int pxi = (pix0w + p * 2 + ps) & (HWSZ - 1);
            int i = pxi >> 7, j = pxi & 127;
            uint u = pk2bf(xp0[pxi], xp0[pxi + HWSZ]);
            *(uint*)(xw + ((i + 1) * PADW + (j + 1)) * 64 + c2 * 2) = u;
        }
    } else {
        int idx = (blockIdx.x - 128) * 256 + t;
        if (idx >= 264192) return;
        ushort* buf = (idx >= 132096) ? y1t : xtt;
        int e_all = idx % 132096;
        int bq = e_all / 33024, e = e_all % 33024;
        int i, j, c;
        if (e < 8320)       { i = 0;   j = e >> 6; c = e & 63; }
        else if (e < 16640) { int e2 = e - 8320; i = 129; j = e2 >> 6; c = e2 & 63; }
        else                { int e2 = e - 16640; c = e2 & 63;
                              i = (e2 >> 7) + 1; j = ((e2 >> 6) & 1) ? 129 : 0; }
        buf[(size_t)bq * SLAB + (i * PADW + j) * 64 + c] = 0;
    }
}

// ---------------------------------------------------------------------------
// prep_w (layer split by explicit subtraction — sizes are not powers of 2)
// ---------------------------------------------------------------------------
__global__ void prep_w(
    const float* __restrict__ wc1, const float* __restrict__ wp1, const float* __restrict__ wm1,
    const float* __restrict__ wc2, const float* __restrict__ wp2, const float* __restrict__ wm2,
    ushort* __restrict__ wdf1, ushort* __restrict__ wof1,
    ushort* __restrict__ wdf2, ushort* __restrict__ wof2)
{
    int idx0 = blockIdx.x * 256 + threadIdx.x;
    union { __hip_bfloat16 h; ushort u; } cv;
    if (idx0 < 73728) {
        int lay = idx0 >= 36864;
        int idx = idx0 - lay * 36864;
        const float* wc = lay ? wc2 : wc1;
        ushort* dst = lay ? wdf2 : wdf1;
        int j = idx & 7, l = (idx >> 3) & 63;
        int nt = (idx >> 9) & 3, kc = (idx >> 11) & 1, tap = idx >> 12;
        int c  = kc * 32 + (l >> 4) * 8 + j;
        int oc = nt * 16 + (l & 15);
        cv.h = __float2bfloat16(wc[(oc * 64 + c) * 9 + tap]);
        dst[idx] = cv.u;
    } else if (idx0 < 110592) {
        int r = idx0 - 73728;
        int lay = r >= 18432;
        int idx = r - lay * 18432;
        const float* wp = lay ? wp2 : wp1;
        const float* wm = lay ? wm2 : wm1;
        ushort* dst = lay ? wof2 : wof1;
        int j = idx & 7, l = (idx >> 3) & 63;
        int nt = (idx >> 9) & 1, kc = (idx >> 10) & 1, tap = idx >> 11;
        int c  = kc * 32 + (l >> 4) * 8 + j;
        int ch = nt * 16 + (l & 15);
        float v = 0.f;
        if (ch < 18)      v = wp[(ch * 64 + c) * 9 + tap];
        else if (ch < 27) v = wm[((ch - 18) * 64 + c) * 9 + tap];
        cv.h = __float2bfloat16(v);
        dst[idx] = cv.u;
    }
}

// ---------------------------------------------------------------------------
// Fused layer, LDS-windowed. Block = 256 thr / 4 waves, 8x16 px patch.
// Wave wv owns rows {2wv, 2wv+1} x 16 cols (2 A-groups of 16 px).
//  stage: 16x24-cell window (48KB) of padded bf16 image -> LDS, chunk-swizzled
//  phase 1: offset/mask conv, A from window LDS, MFMA -> omW
//  phase 2: per tap: coords; gather corners via swizzled ds_read_b128
//           (global fallback when corner outside window); combine; 16 MFMA
// ---------------------------------------------------------------------------
__global__ __launch_bounds__(256, 2) void fused(
    const ushort* __restrict__ xt, const ushort* __restrict__ wof,
    const float* __restrict__ bp, const float* __restrict__ bm,
    const ushort* __restrict__ wdf, const float* __restrict__ xres,
    float* __restrict__ outn, ushort* __restrict__ y1t, int mode)
{
    __shared__ __align__(16) char sm[SM_BYTES];
    const int t = threadIdx.x, l = t & 63, wv = t >> 6;
    // XCD swizzle: 512 blocks, 64 per XCD contiguous
    const int lb = (blockIdx.x & 7) * 64 + (blockIdx.x >> 3);
    const int bb = lb >> 7;                  // batch
    const int patch = lb & 127;              // 16 x 8 patches
    const int i0 = (patch >> 3) * 8;         // output row base (8 rows)
    const int j0 = (patch & 7) * 16;         // output col base (16 cols)
    const int pc = l & 15, ck = l >> 4;      // lane's pixel-col / channel-chunk
    const ushort* xb = xt + (size_t)bb * SLAB;
    const char* xbb = (const char*)xb;

    // ---------- stage window ----------
    for (int s = t; s < 3072; s += 256) {
        int q = s & 7, cq = s >> 3;
        int c = cq % WC, r = cq / WC;
        int ip = min(max(i0 - 2 + r, 0), 129);
        int jp = min(max(j0 - 2 + c, 0), 129);
        uint4 v = *(const uint4*)(xbb + ((ip * PADW + jp) << 7) + (q << 4));
        *(uint4*)(sm + ((r * WC + c) << 7) + (((q ^ ((r + c) & 7))) << 4)) = v;
    }
    __syncthreads();

    // ---------- phase 1: offset/mask conv ----------
    f32x4 z4 = {0.f, 0.f, 0.f, 0.f};
    f32x4 oa[2][2];
    oa[0][0] = z4; oa[0][1] = z4; oa[1][0] = z4; oa[1][1] = z4;
    #pragma unroll
    for (int tap = 0; tap < 9; ++tap) {
        int ti = tap / 3, tj = tap - ti * 3;
        short8 b00 = *(const short8*)(wof + (tap * 4 + 0) * 512 + l * 8);
        short8 b01 = *(const short8*)(wof + (tap * 4 + 1) * 512 + l * 8);
        short8 b10 = *(const short8*)(wof + (tap * 4 + 2) * 512 + l * 8);
        short8 b11 = *(const short8*)(wof + (tap * 4 + 3) * 512 + l * 8);
        #pragma unroll
        for (int ag = 0; ag < 2; ++ag) {
            int rA = 2 * wv + ag + ti + 2;
            int cA = pc + tj + 2;
            int hA = (rA + cA) & 7;
            const char* cb = sm + ((rA * WC + cA) << 7);
            short8 a0 = *(const short8*)(cb + ((ck ^ hA) << 4));
            short8 a1 = *(const short8*)(cb + (((ck + 4) ^ hA) << 4));
            oa[ag][0] = __builtin_amdgcn_mfma_f32_16x16x32_bf16(a0, b00, oa[ag][0], 0, 0, 0);
            oa[ag][1] = __builtin_amdgcn_mfma_f32_16x16x32_bf16(a0, b01, oa[ag][1], 0, 0, 0);
            oa[ag][0] = __builtin_amdgcn_mfma_f32_16x16x32_bf16(a1, b10, oa[ag][0], 0, 0, 0);
            oa[ag][1] = __builtin_amdgcn_mfma_f32_16x16x32_bf16(a1, b11, oa[ag][1], 0, 0, 0);
        }
    }
    float* omW = (float*)(sm + OMW_OFF) + wv * 891;   // [27][33] per wave
    #pragma unroll
    for (int ag = 0; ag < 2; ++ag)
        #pragma unroll
        for (int nt = 0; nt < 2; ++nt) {
            int ch = nt * 16 + pc;               // D: col = lane&15 = channel
            #pragma unroll
            for (int r = 0; r < 4; ++r) {
                if (ch < 27) {
                    float v = oa[ag][nt][r] + ((ch < 18) ? bp[ch] : bm[ch - 18]);
                    if (ch >= 18) v = 1.f / (1.f + __expf(-v));
                    omW[ch * 33 + ag * 16 + ck * 4 + r] = v;   // D: row = px16
                }
            }
        }

    // ---------- phase 2: deformable sampling + contraction ----------
    f32x4 acc[2][4];
    #pragma unroll
    for (int ag = 0; ag < 2; ++ag)
        #pragma unroll
        for (int nt = 0; nt < 4; ++nt) acc[ag][nt] = z4;

    const char* pb = xbb + ck * 16;
    #pragma unroll
    for (int n = 0; n < 9; ++n) {
        const ushort* wbase = wdf + (size_t)n * 4096 + l * 8;
        short8 w00 = *(const short8*)(wbase);
        short8 w01 = *(const short8*)(wbase + 512);
        short8 w02 = *(const short8*)(wbase + 1024);
        short8 w03 = *(const short8*)(wbase + 1536);
        short8 w10 = *(const short8*)(wbase + 2048);
        short8 w11 = *(const short8*)(wbase + 2560);
        short8 w12 = *(const short8*)(wbase + 3072);
        short8 w13 = *(const short8*)(wbase + 3584);
        #pragma unroll
        for (int ag = 0; ag < 2; ++ag) {
            int4 cc; float4 g;
            coords_tap(omW, ag * 16 + pc, i0 + 2 * wv + ag, j0 + pc, n, cc, g);
            int rlt = cc.x - (i0 - 2), clt = cc.y - (j0 - 2);
            int rrb = cc.z - (i0 - 2), crb = cc.w - (j0 - 2);
            bool ok = ((uint)rlt < (uint)WR) & ((uint)rrb < (uint)WR) &
                      ((uint)clt < (uint)WC) & ((uint)crb < (uint)WC);
            short8 dltl, dlth, drbl, drbh, dlbl, dlbh, drtl, drth;
            if (ok) {
                int hlt = (rlt + clt) & 7, hrb = (rrb + crb) & 7;
                int hlb = (rlt + crb) & 7, hrt = (rrb + clt) & 7;
                const char* blt = sm + ((rlt * WC + clt) << 7);
                const char* brb = sm + ((rrb * WC + crb) << 7);
                const char* blb = sm + ((rlt * WC + crb) << 7);
                const char* brt = sm + ((rrb * WC + clt) << 7);
                dltl = *(const short8*)(blt + ((ck ^ hlt) << 4));
                dlth = *(const short8*)(blt + (((ck + 4) ^ hlt) << 4));
                drbl = *(const short8*)(brb + ((ck ^ hrb) << 4));
                drbh = *(const short8*)(brb + (((ck + 4) ^ hrb) << 4));
                dlbl = *(const short8*)(blb + ((ck ^ hlb) << 4));
                dlbh = *(const short8*)(blb + (((ck + 4) ^ hlb) << 4));
                drtl = *(const short8*)(brt + ((ck ^ hrt) << 4));
                drth = *(const short8*)(brt + (((ck + 4) ^ hrt) << 4));
            } else {
                int o_lt = (cc.x * PADW + cc.y) << 7;
                int o_rb = (cc.z * PADW + cc.w) << 7;
                int o_lb = (cc.x * PADW + cc.w) << 7;
                int o_rt = (cc.z * PADW + cc.y) << 7;
                dltl = *(const short8*)(pb + o_lt); dlth = *(const short8*)(pb + o_lt + 64);
                drbl = *(const short8*)(pb + o_rb); drbh = *(const short8*)(pb + o_rb + 64);
                dlbl = *(const short8*)(pb + o_lb); dlbh = *(const short8*)(pb + o_lb + 64);
                drtl = *(const short8*)(pb + o_rt); drth = *(const short8*)(pb + o_rt + 64);
            }
            short8 a0 = combine4(dltl, drbl, dlbl, drtl, g.x, g.y, g.z, g.w);
            short8 a1 = combine4(dlth, drbh, dlbh, drth, g.x, g.y, g.z, g.w);
            acc[ag][0] = __builtin_amdgcn_mfma_f32_16x16x32_bf16(a0, w00, acc[ag][0], 0, 0, 0);
            acc[ag][1] = __builtin_amdgcn_mfma_f32_16x16x32_bf16(a0, w01, acc[ag][1], 0, 0, 0);
            acc[ag][2] = __builtin_amdgcn_mfma_f32_16x16x32_bf16(a0, w02, acc[ag][2], 0, 0, 0);
            acc[ag][3] = __builtin_amdgcn_mfma_f32_16x16x32_bf16(a0, w03, acc[ag][3], 0, 0, 0);
            acc[ag][0] = __builtin_amdgcn_mfma_f32_16x16x32_bf16(a1, w10, acc[ag][0], 0, 0, 0);
            acc[ag][1] = __builtin_amdgcn_mfma_f32_16x16x32_bf16(a1, w11, acc[ag][1], 0, 0, 0);
            acc[ag][2] = __builtin_amdgcn_mfma_f32_16x16x32_bf16(a1, w12, acc[ag][2], 0, 0, 0);
            acc[ag][3] = __builtin_amdgcn_mfma_f32_16x16x32_bf16(a1, w13, acc[ag][3], 0, 0, 0);
        }
    }

    // ---------- epilogue ----------
    if (mode == 0) {
        #pragma unroll
        for (int ag = 0; ag < 2; ++ag)
            #pragma unroll
            for (int nt = 0; nt < 4; ++nt) {
                int oc = nt * 16 + pc;           // D: col = oc
                int orow = i0 + 2 * wv + ag;
                size_t o = ((size_t)(bb * 64 + oc)) * HWSZ + orow * 128 + j0 + ck * 4;
                float4 rsd = *(const float4*)(xres + o);
                float4 vv;
                vv.x = acc[ag][nt][0] + rsd.x; vv.y = acc[ag][nt][1] + rsd.y;
                vv.z = acc[ag][nt][2] + rsd.z; vv.w = acc[ag][nt][3] + rsd.w;
                *(float4*)(outn + o) = vv;
            }
    } else {
        __syncthreads();
        float* T = (float*)sm;                   // [64 oc][130] (reuses window)
        #pragma unroll
        for (int ag = 0; ag < 2; ++ag)
            #pragma unroll
            for (int nt = 0; nt < 4; ++nt) {
                int oc = nt * 16 + pc;
                #pragma unroll
                for (int r = 0; r < 4; ++r) {
                    int plin = (2 * wv + ag) * 16 + ck * 4 + r;
                    T[oc * 130 + plin] = fmaxf(acc[ag][nt][r], 0.f);
                }
            }
        __syncthreads();
        int px = t >> 1, oc0 = (t & 1) * 32;
        int prow = px >> 4, pcol = px & 15;
        ushort* dst = y1t + (size_t)bb * SLAB +
                      ((i0 + prow + 1) * PADW + (j0 + pcol + 1)) * 64 + oc0;
        uint w[16];
        #pragma unroll
        for (int k2 = 0; k2 < 16; ++k2)
            w[k2] = pk2bf(T[(oc0 + k2 * 2) * 130 + px], T[(oc0 + k2 * 2 + 1) * 130 + px]);
        *(uint4*)dst       = make_uint4(w[0],  w[1],  w[2],  w[3]);
        *(uint4*)(dst + 8) = make_uint4(w[4],  w[5],  w[6],  w[7]);
        *(uint4*)(dst + 16)= make_uint4(w[8],  w[9],  w[10], w[11]);
        *(uint4*)(dst + 24)= make_uint4(w[12], w[13], w[14], w[15]);
    }
}

// ---------------------------------------------------------------------------
extern "C" void kernel_launch(void* const* d_in, const int* in_sizes, int n_in,
                              void* d_out, int out_size, void* d_ws, size_t ws_size,
                              hipStream_t stream)
{
    const float* x      = (const float*)d_in[0];
    const float* d1_w_p = (const float*)d_in[1];
    const float* d1_b_p = (const float*)d_in[2];
    const float* d1_w_m = (const float*)d_in[3];
    const float* d1_b_m = (const float*)d_in[4];
    const float* d1_w_c = (const float*)d_in[5];
    const float* d2_w_p = (const float*)d_in[6];
    const float* d2_b_p = (const float*)d_in[7];
    const float* d2_w_m = (const float*)d_in[8];
    const float* d2_b_m = (const float*)d_in[9];
    const float* d2_w_c = (const float*)d_in[10];
    float* out = (float*)d_out;

    char* ws = (char*)d_ws;
    ushort* xtt  = (ushort*)(ws);               //  8,652,800 B padded NHWC bf16 x
    ushort* y1t  = (ushort*)(ws + 8652800);     //  8,652,800 B padded NHWC bf16 y1
    ushort* wdf1 = (ushort*)(ws + 17305600);
    ushort* wof1 = (ushort*)(ws + 17379328);
    ushort* wdf2 = (ushort*)(ws + 17416192);
    ushort* wof2 = (ushort*)(ws + 17489920);

    prep_w<<<432, 256, 0, stream>>>(d1_w_c, d1_w_p, d1_w_m, d2_w_c, d2_w_p, d2_w_m,
                                    wdf1, wof1, wdf2, wof2);
    prep_x<<<1160, 256, 0, stream>>>(x, xtt, y1t);

    fused<<<512, 256, 0, stream>>>(xtt, wof1, d1_b_p, d1_b_m, wdf1,
                                   nullptr, nullptr, y1t, 1);
    fused<<<512, 256, 0, stream>>>(y1t, wof2, d2_b_p, d2_b_m, wdf2,
                                   x, out, nullptr, 0);
}